// Round 4
// baseline (123.624 us; speedup 1.0000x reference)
//
#include <hip/hip_runtime.h>
#include <hip/hip_bf16.h>
#include <stdint.h>

// Locally-connected layer: X[128,32,32,64] f32, filters[900,576,64] f32
// -> out[128,30,30,64] f32.  900 per-location GEMMs: M=128 x N=64 x K=576.
// One WG per location, 512 threads = 8 waves (R4): each wave owns a 16x64
// output strip. Same 48KB double-buffered LDS pipeline as R2 (1-deep register
// prefetch, one barrier per K-step), but 3 WG/CU now = 24 waves/CU (was 12).
// R3 post-mortem: deeper ILP prefetch cost VGPR/occupancy and regressed;
// latency hiding here must come from TLP.

typedef __attribute__((ext_vector_type(4))) float  f32x4;
typedef __attribute__((ext_vector_type(8))) short  short8;
typedef __attribute__((ext_vector_type(4))) short  short4v;

#define BOFF 16384  // byte offset of B tile inside one LDS buffer

// XOR swizzle on 16B chunks within a 128B row (uniform bank spread for all
// staging writes + fragment b128 reads).
__device__ __forceinline__ uint32_t swz_addr(uint32_t row, uint32_t inrow) {
    uint32_t chunk = inrow >> 4;
    uint32_t rem   = inrow & 15u;
    return row * 128u + (((chunk ^ row ^ (row >> 3)) & 7u) << 4) + rem;
}

__device__ __forceinline__ short f2bf(float x) {
    __hip_bfloat16 h = __float2bfloat16(x);
    short r;
    __builtin_memcpy(&r, &h, 2);
    return r;
}

__global__ __launch_bounds__(512, 6)
void lc_mfma_kernel(const float* __restrict__ X,
                    const float* __restrict__ Fl,
                    float* __restrict__ Out) {
    __shared__ __align__(16) unsigned char lds[2][24576];
    // each buffer: [0,16384) A tile 128rows x 64 bf16 (swizzled)
    //              [16384,24576) B tile 64rows(fout) x 64 bf16 (swizzled)

    // Bijective XCD-chunked swizzle: 8 XCDs, nwg=900 -> q=112, r=4.
    const int orig = blockIdx.x;
    const int xcd  = orig & 7;
    const int idx  = orig >> 3;
    const int l    = (xcd < 4 ? xcd * 113 : 452 + (xcd - 4) * 112) + idx;

    const int oi = l / 30;
    const int oj = l % 30;
    const int tid  = threadIdx.x;
    const int lane = tid & 63;
    const int wave = tid >> 6;          // 0..7, owns rows wave*16..+15

    f32x4 acc[4];
#pragma unroll
    for (int n = 0; n < 4; ++n)
        acc[n] = f32x4{0.f, 0.f, 0.f, 0.f};

    // A staging: thread covers row ar (0..127), fin quarter aq*16..+15
    const int ar = tid >> 2;
    const int aq = tid & 3;
    // B staging: waves 4..7 only; thread covers f = fq*4..+3, k = k0..k0+3
    const int fq = tid & 15;
    const int k0 = ((tid >> 4) & 15) * 4;
    const bool bthread = (tid >= 256);

    const float* Fb = Fl + (size_t)l * (576 * 64);

    float4 av[4];  // prefetched A regs (1 row-quarter)
    float4 bv[4];  // prefetched B regs (4 k-rows, waves 4..7)

#define ISSUE_LOADS(S)                                                          \
    do {                                                                        \
        const int di_ = (S) / 3, dj_ = (S) % 3;                                 \
        const int h_ = oi + di_, w_ = oj + dj_;                                 \
        const float* a_ = X + (((size_t)ar * 32 + h_) * 32 + w_) * 64 + aq*16;  \
        av[0] = ((const float4*)a_)[0]; av[1] = ((const float4*)a_)[1];         \
        av[2] = ((const float4*)a_)[2]; av[3] = ((const float4*)a_)[3];         \
        if (bthread) {                                                          \
            const float* b_ = Fb + (size_t)(S) * 4096 + (size_t)k0 * 64 + fq*4; \
            bv[0] = *(const float4*)(b_);       bv[1] = *(const float4*)(b_ + 64);  \
            bv[2] = *(const float4*)(b_ + 128); bv[3] = *(const float4*)(b_ + 192); \
        }                                                                       \
    } while (0)

#define WRITE_LDS(BUF)                                                          \
    do {                                                                        \
        unsigned char* L_ = lds[BUF];                                           \
        short8 p0, p1;                                                          \
        p0[0]=f2bf(av[0].x); p0[1]=f2bf(av[0].y); p0[2]=f2bf(av[0].z); p0[3]=f2bf(av[0].w); \
        p0[4]=f2bf(av[1].x); p0[5]=f2bf(av[1].y); p0[6]=f2bf(av[1].z); p0[7]=f2bf(av[1].w); \
        p1[0]=f2bf(av[2].x); p1[1]=f2bf(av[2].y); p1[2]=f2bf(av[2].z); p1[3]=f2bf(av[2].w); \
        p1[4]=f2bf(av[3].x); p1[5]=f2bf(av[3].y); p1[6]=f2bf(av[3].z); p1[7]=f2bf(av[3].w); \
        *(short8*)&L_[swz_addr(ar, aq*32 + 0 )] = p0;                           \
        *(short8*)&L_[swz_addr(ar, aq*32 + 16)] = p1;                           \
        if (bthread) {                                                          \
            const short4v c0 = { f2bf(bv[0].x), f2bf(bv[1].x), f2bf(bv[2].x), f2bf(bv[3].x) }; \
            const short4v c1 = { f2bf(bv[0].y), f2bf(bv[1].y), f2bf(bv[2].y), f2bf(bv[3].y) }; \
            const short4v c2 = { f2bf(bv[0].z), f2bf(bv[1].z), f2bf(bv[2].z), f2bf(bv[3].z) }; \
            const short4v c3 = { f2bf(bv[0].w), f2bf(bv[1].w), f2bf(bv[2].w), f2bf(bv[3].w) }; \
            *(short4v*)&L_[BOFF + swz_addr(fq*4 + 0, k0*2)] = c0;               \
            *(short4v*)&L_[BOFF + swz_addr(fq*4 + 1, k0*2)] = c1;               \
            *(short4v*)&L_[BOFF + swz_addr(fq*4 + 2, k0*2)] = c2;               \
            *(short4v*)&L_[BOFF + swz_addr(fq*4 + 3, k0*2)] = c3;               \
        }                                                                       \
    } while (0)

    // prologue: stage step 0 into buffer 0
    ISSUE_LOADS(0);
    WRITE_LDS(0);

    const int mb   = wave * 16;
    const int rsel = lane & 15;
    const int ksel = (lane >> 4) * 16;

#pragma unroll 1
    for (int s = 0; s < 9; ++s) {
        // issue next step's loads BEFORE barrier+compute; vmcnt wait lands at
        // WRITE_LDS below (hidden under barrier + ds_read + MFMA)
        if (s < 8) ISSUE_LOADS(s + 1);

        __syncthreads();  // lds[s&1] writes (prev iter / prologue) visible

        const unsigned char* L = lds[s & 1];
#pragma unroll
        for (int kk = 0; kk < 2; ++kk) {
            const uint32_t inrow = (uint32_t)(kk * 64 + ksel);
            const short8 a0 = *(const short8*)&L[swz_addr(mb + rsel, inrow)];
            const short8 b0 = *(const short8*)&L[BOFF + swz_addr(     rsel, inrow)];
            const short8 b1 = *(const short8*)&L[BOFF + swz_addr(16 + rsel, inrow)];
            const short8 b2 = *(const short8*)&L[BOFF + swz_addr(32 + rsel, inrow)];
            const short8 b3 = *(const short8*)&L[BOFF + swz_addr(48 + rsel, inrow)];
            acc[0] = __builtin_amdgcn_mfma_f32_16x16x32_bf16(a0, b0, acc[0], 0, 0, 0);
            acc[1] = __builtin_amdgcn_mfma_f32_16x16x32_bf16(a0, b1, acc[1], 0, 0, 0);
            acc[2] = __builtin_amdgcn_mfma_f32_16x16x32_bf16(a0, b2, acc[2], 0, 0, 0);
            acc[3] = __builtin_amdgcn_mfma_f32_16x16x32_bf16(a0, b3, acc[3], 0, 0, 0);
        }

        // write step s+1 into the other buffer; its previous readers all
        // passed the barrier above. One barrier per step total.
        if (s < 8) WRITE_LDS((s + 1) & 1);
    }

    // epilogue: D layout col=lane&15, row=(lane>>4)*4+reg (m89-verified)
    const int col = lane & 15;
    const int rb  = (lane >> 4) * 4;
#pragma unroll
    for (int n = 0; n < 4; ++n)
#pragma unroll
        for (int i = 0; i < 4; ++i) {
            const int row = mb + rb + i;      // batch index
            const int f   = n * 16 + col;     // fout index
            Out[((size_t)row * 900 + l) * 64 + f] = acc[n][i];
        }
}

extern "C" void kernel_launch(void* const* d_in, const int* in_sizes, int n_in,
                              void* d_out, int out_size, void* d_ws, size_t ws_size,
                              hipStream_t stream) {
    const float* X  = (const float*)d_in[0];   // [128,32,32,64]
    const float* Fl = (const float*)d_in[1];   // [900,576,64]
    float* Out = (float*)d_out;                // [128,30,30,64]
    lc_mfma_kernel<<<dim3(900), dim3(512), 0, stream>>>(X, Fl, Out);
}

// Round 5
// 40.455 us; speedup vs baseline: 3.0558x; 3.0558x over previous
//
#include <hip/hip_runtime.h>
#include <hip/hip_bf16.h>
#include <stdint.h>

// Locally-connected layer: X[128,32,32,64] f32, filters[900,576,64] f32
// -> out[128,30,30,64] f32.  900 per-location GEMMs: M=128 x N=64 x K=576.
// One WG per location, 512 threads = 8 waves; each wave owns a 16x64 output
// strip. Double-buffered 48KB LDS, 1-deep register prefetch, one barrier per
// K-step, bijective XCD-chunked swizzle.
// R4 post-mortem: __launch_bounds__(512,6) forced VGPR=40 -> prefetch arrays
// spilled to scratch (WRITE_SIZE 28.8->192MB). R5: cut register need to ~55
// (B staged by all 512 threads, 2 float4 each) and relax bounds to (512,4).

typedef __attribute__((ext_vector_type(4))) float  f32x4;
typedef __attribute__((ext_vector_type(8))) short  short8;

#define BOFF 16384  // byte offset of B tile inside one LDS buffer

// XOR swizzle on 16B chunks within a 128B row.
__device__ __forceinline__ uint32_t swz_addr(uint32_t row, uint32_t inrow) {
    uint32_t chunk = inrow >> 4;
    uint32_t rem   = inrow & 15u;
    return row * 128u + (((chunk ^ row ^ (row >> 3)) & 7u) << 4) + rem;
}

__device__ __forceinline__ uint16_t f2bf_u(float x) {
    __hip_bfloat16 h = __float2bfloat16(x);
    uint16_t r;
    __builtin_memcpy(&r, &h, 2);
    return r;
}
__device__ __forceinline__ short f2bf(float x) { return (short)f2bf_u(x); }
__device__ __forceinline__ uint32_t pack2bf(float lo, float hi) {
    return (uint32_t)f2bf_u(lo) | ((uint32_t)f2bf_u(hi) << 16);
}

__global__ __launch_bounds__(512, 4)
void lc_mfma_kernel(const float* __restrict__ X,
                    const float* __restrict__ Fl,
                    float* __restrict__ Out) {
    __shared__ __align__(16) unsigned char lds[2][24576];
    // each buffer: [0,16384) A tile 128rows x 64 bf16 (swizzled)
    //              [16384,24576) B tile 64rows(fout) x 64 bf16 (swizzled)

    // Bijective XCD-chunked swizzle: 8 XCDs, nwg=900 -> q=112, r=4.
    const int orig = blockIdx.x;
    const int xcd  = orig & 7;
    const int idx  = orig >> 3;
    const int l    = (xcd < 4 ? xcd * 113 : 452 + (xcd - 4) * 112) + idx;

    const int oi = l / 30;
    const int oj = l % 30;
    const int tid  = threadIdx.x;
    const int lane = tid & 63;
    const int wave = tid >> 6;          // 0..7, owns rows wave*16..+15

    f32x4 acc[4];
#pragma unroll
    for (int n = 0; n < 4; ++n)
        acc[n] = f32x4{0.f, 0.f, 0.f, 0.f};

    // A staging: thread covers row ar (0..127), fin quarter aq*16..+15
    const int ar = tid >> 2;
    const int aq = tid & 3;
    // B staging (all 512 threads): f block fq*4..+3, k pair kp*2, kp = 0..31
    const int fq = tid & 15;
    const int kp = tid >> 4;            // 0..31

    const float* Fb = Fl + (size_t)l * (576 * 64);

    float4 av[4];  // prefetched A regs (1 row-quarter, 16 fin)
    float4 bv[2];  // prefetched B regs (2 k-rows x 4 f)

#define ISSUE_LOADS(S)                                                          \
    do {                                                                        \
        const int di_ = (S) / 3, dj_ = (S) % 3;                                 \
        const int h_ = oi + di_, w_ = oj + dj_;                                 \
        const float* a_ = X + (((size_t)ar * 32 + h_) * 32 + w_) * 64 + aq*16;  \
        av[0] = ((const float4*)a_)[0]; av[1] = ((const float4*)a_)[1];         \
        av[2] = ((const float4*)a_)[2]; av[3] = ((const float4*)a_)[3];         \
        const float* b_ = Fb + (size_t)(S) * 4096 + (size_t)(kp*2) * 64 + fq*4; \
        bv[0] = *(const float4*)(b_);                                           \
        bv[1] = *(const float4*)(b_ + 64);                                      \
    } while (0)

#define WRITE_LDS(BUF)                                                          \
    do {                                                                        \
        unsigned char* L_ = lds[BUF];                                           \
        short8 p0, p1;                                                          \
        p0[0]=f2bf(av[0].x); p0[1]=f2bf(av[0].y); p0[2]=f2bf(av[0].z); p0[3]=f2bf(av[0].w); \
        p0[4]=f2bf(av[1].x); p0[5]=f2bf(av[1].y); p0[6]=f2bf(av[1].z); p0[7]=f2bf(av[1].w); \
        p1[0]=f2bf(av[2].x); p1[1]=f2bf(av[2].y); p1[2]=f2bf(av[2].z); p1[3]=f2bf(av[2].w); \
        p1[4]=f2bf(av[3].x); p1[5]=f2bf(av[3].y); p1[6]=f2bf(av[3].z); p1[7]=f2bf(av[3].w); \
        *(short8*)&L_[swz_addr(ar, aq*32 + 0 )] = p0;                           \
        *(short8*)&L_[swz_addr(ar, aq*32 + 16)] = p1;                           \
        /* B transposed: Blds[f][k] bf16; pack (k=kp*2, kp*2+1) into one b32 */ \
        *(uint32_t*)&L_[BOFF + swz_addr(fq*4 + 0, kp*4)] = pack2bf(bv[0].x, bv[1].x); \
        *(uint32_t*)&L_[BOFF + swz_addr(fq*4 + 1, kp*4)] = pack2bf(bv[0].y, bv[1].y); \
        *(uint32_t*)&L_[BOFF + swz_addr(fq*4 + 2, kp*4)] = pack2bf(bv[0].z, bv[1].z); \
        *(uint32_t*)&L_[BOFF + swz_addr(fq*4 + 3, kp*4)] = pack2bf(bv[0].w, bv[1].w); \
    } while (0)

    // prologue: stage step 0 into buffer 0
    ISSUE_LOADS(0);
    WRITE_LDS(0);

    const int mb   = wave * 16;
    const int rsel = lane & 15;
    const int ksel = (lane >> 4) * 16;

#pragma unroll 1
    for (int s = 0; s < 9; ++s) {
        // issue next step's loads BEFORE barrier+compute; vmcnt wait lands at
        // WRITE_LDS below (hidden under barrier + ds_read + MFMA)
        if (s < 8) ISSUE_LOADS(s + 1);

        __syncthreads();  // lds[s&1] writes (prev iter / prologue) visible

        const unsigned char* L = lds[s & 1];
#pragma unroll
        for (int kk = 0; kk < 2; ++kk) {
            const uint32_t inrow = (uint32_t)(kk * 64 + ksel);
            const short8 a0 = *(const short8*)&L[swz_addr(mb + rsel, inrow)];
            const short8 b0 = *(const short8*)&L[BOFF + swz_addr(     rsel, inrow)];
            const short8 b1 = *(const short8*)&L[BOFF + swz_addr(16 + rsel, inrow)];
            const short8 b2 = *(const short8*)&L[BOFF + swz_addr(32 + rsel, inrow)];
            const short8 b3 = *(const short8*)&L[BOFF + swz_addr(48 + rsel, inrow)];
            acc[0] = __builtin_amdgcn_mfma_f32_16x16x32_bf16(a0, b0, acc[0], 0, 0, 0);
            acc[1] = __builtin_amdgcn_mfma_f32_16x16x32_bf16(a0, b1, acc[1], 0, 0, 0);
            acc[2] = __builtin_amdgcn_mfma_f32_16x16x32_bf16(a0, b2, acc[2], 0, 0, 0);
            acc[3] = __builtin_amdgcn_mfma_f32_16x16x32_bf16(a0, b3, acc[3], 0, 0, 0);
        }

        // write step s+1 into the other buffer; its previous readers all
        // passed the barrier above. One barrier per step total.
        if (s < 8) WRITE_LDS((s + 1) & 1);
    }

    // epilogue: D layout col=lane&15, row=(lane>>4)*4+reg (m89-verified)
    const int col = lane & 15;
    const int rb  = (lane >> 4) * 4;
#pragma unroll
    for (int n = 0; n < 4; ++n)
#pragma unroll
        for (int i = 0; i < 4; ++i) {
            const int row = mb + rb + i;      // batch index
            const int f   = n * 16 + col;     // fout index
            Out[((size_t)row * 900 + l) * 64 + f] = acc[n][i];
        }
}

extern "C" void kernel_launch(void* const* d_in, const int* in_sizes, int n_in,
                              void* d_out, int out_size, void* d_ws, size_t ws_size,
                              hipStream_t stream) {
    const float* X  = (const float*)d_in[0];   // [128,32,32,64]
    const float* Fl = (const float*)d_in[1];   // [900,576,64]
    float* Out = (float*)d_out;                // [128,30,30,64]
    lc_mfma_kernel<<<dim3(900), dim3(512), 0, stream>>>(X, Fl, Out);
}